// Round 12
// baseline (632.277 us; speedup 1.0000x reference)
//
#include <hip/hip_runtime.h>
#include <hip/hip_bf16.h>
#include <math.h>

#define N_NODES   100000
#define N_EDGES   1600000
#define N_GRAPHS  64
#define NF_D      140
#define OP_EMB_D  32
#define CFG_D     18
#define K_EMB     192     // 190 zero-padded to 192
#define NB_SCAN   391     // ceil(N_NODES/256)
// co-resident merged grids (<= 2048 blocks = 8 x 256CU residency)
#define HC_HIST   1024    // hist role blocks (grid-stride over edges)
#define HC_CONCAT 1022    // concat role blocks
#define FE_FILL   1264    // fill role blocks (158 groups x 8 ranges)
#define GEMM_BLKS 782     // embed-GEMM role blocks ((3125+3)/4)

typedef __attribute__((ext_vector_type(8))) short short8;   // 8 bf16 = 4 VGPRs
typedef __attribute__((ext_vector_type(4))) float f32x4;    // MFMA C/D frag

// monotone float<->uint encoding for atomicMax on floats
__device__ __forceinline__ unsigned fenc(float f) {
    unsigned u = __float_as_uint(f);
    return (u & 0x80000000u) ? ~u : (u | 0x80000000u);
}
__device__ __forceinline__ float fdec(unsigned u) {
    unsigned v = (u & 0x80000000u) ? (u & 0x7FFFFFFFu) : ~u;
    return __uint_as_float(v);
}
// self-contained bf16 pack/unpack (RNE; finite inputs only)
__device__ __forceinline__ unsigned short f2bf(float f) {
    unsigned u = __float_as_uint(f);
    return (unsigned short)((u + 0x7FFFu + ((u >> 16) & 1u)) >> 16);
}
__device__ __forceinline__ float bf2f(unsigned short h) {
    return __uint_as_float((unsigned)h << 16);
}
__device__ __forceinline__ short8 ld_frag(const unsigned short* p) {
    union { uint4 u; short8 s; } c;
    c.u = *(const uint4*)p;
    return c.s;
}

// ---------------- CSR build + overlap notes ----------------
// Measured model (R2..R11): device-scope atomics cost ~40B WRITE + latency
// slot at the memory-side coherence point; L2-locality tricks null. R8's
// "hist||concat = sum" was re-diagnosed in R11: with 10K blocks and 2048
// resident, CONTIGUOUS role ranges execute sequentially through the block
// scheduler — the merge never co-scheduled. R12 fix: shrink both merged
// grids to <= 2046 blocks so both roles are co-resident by construction
// (hist/fill waves idle on latency; concat/GEMM waves fill the bubbles).

// ---------------- GEMM body (device fn, shared by standalone + merged) ----
// A-operand = packed weights (m = weight-col), B-operand = node rows.
// D layout (m89/m91): col=lane&15 = node, row=quad*4+reg = weight-col.
// One wave = 32 nodes x all M cols; K fully unrolled; no LDS, no barriers.
template <int M, int K, bool BIAS, bool RELU, bool OBF16>
__device__ __forceinline__ void gemm_body(
    const unsigned short* __restrict__ x,
    const unsigned short* __restrict__ wpk, const float* __restrict__ b,
    void* __restrict__ outv, int N, int bid)
{
    constexpr int MT = M / 16;
    constexpr int KC = K / 32;
    const int tid = threadIdx.x, wave = tid >> 6, lane = tid & 63;
    const int wid = bid * 4 + wave;
    if (wid >= (N >> 5)) return;                  // N % 32 == 0
    const int nb   = wid << 5;
    const int l15  = lane & 15;
    const int quad = lane >> 4;

    f32x4 acc[2][MT];
    #pragma unroll
    for (int mt = 0; mt < MT; ++mt) {
        #pragma unroll
        for (int q = 0; q < 4; ++q) {
            const float bv = BIAS ? b[mt * 16 + quad * 4 + q] : 0.f;
            acc[0][mt][q] = bv;
            acc[1][mt][q] = bv;
        }
    }
    #pragma unroll
    for (int kc = 0; kc < KC; ++kc) {
        const short8 b0 = ld_frag(x + (long long)(nb + l15)      * K + kc * 32 + quad * 8);
        const short8 b1 = ld_frag(x + (long long)(nb + 16 + l15) * K + kc * 32 + quad * 8);
        #pragma unroll
        for (int mt = 0; mt < MT; ++mt) {
            const short8 a = ld_frag(wpk + ((long long)(kc * MT + mt) * 64 + lane) * 8);
            acc[0][mt] = __builtin_amdgcn_mfma_f32_16x16x32_bf16(a, b0, acc[0][mt], 0, 0, 0);
            acc[1][mt] = __builtin_amdgcn_mfma_f32_16x16x32_bf16(a, b1, acc[1][mt], 0, 0, 0);
        }
    }
    #pragma unroll
    for (int s = 0; s < 2; ++s) {
        const long long row = nb + s * 16 + l15;
        if (OBF16) {
            unsigned short* orow = (unsigned short*)outv + row * M;
            #pragma unroll
            for (int mt = 0; mt < MT; ++mt) {
                float f0 = acc[s][mt][0], f1 = acc[s][mt][1];
                float f2 = acc[s][mt][2], f3 = acc[s][mt][3];
                if (RELU) {
                    f0 = fmaxf(f0, 0.f); f1 = fmaxf(f1, 0.f);
                    f2 = fmaxf(f2, 0.f); f3 = fmaxf(f3, 0.f);
                }
                uint2 pk;
                pk.x = ((unsigned)f2bf(f1) << 16) | (unsigned)f2bf(f0);
                pk.y = ((unsigned)f2bf(f3) << 16) | (unsigned)f2bf(f2);
                *(uint2*)(orow + mt * 16 + quad * 4) = pk;
            }
        } else {
            float* orow = (float*)outv + row * M;
            #pragma unroll
            for (int mt = 0; mt < MT; ++mt) {
                f32x4 v = acc[s][mt];
                if (RELU) {
                    v[0] = fmaxf(v[0], 0.f); v[1] = fmaxf(v[1], 0.f);
                    v[2] = fmaxf(v[2], 0.f); v[3] = fmaxf(v[3], 0.f);
                }
                *(f32x4*)(orow + mt * 16 + quad * 4) = v;
            }
        }
    }
}

// ---------------- merged co-resident: hist(+rank) || concat ----------------
// 2046 blocks total (<= residency) -> both roles run concurrently on every
// CU for the whole dispatch. hist grid-strides edges (~6 rounds/thread).
__global__ __launch_bounds__(256) void hist_concat_kernel(
    const int* __restrict__ dst, int* __restrict__ cnt,
    unsigned* __restrict__ rank,
    const float* __restrict__ node_feat, const float* __restrict__ cfg,
    const int* __restrict__ opcode, const float* __restrict__ op_emb,
    unsigned short* __restrict__ x0)
{
    const int g = blockIdx.x;
    if (g < HC_HIST) {
        for (int e = g * 256 + threadIdx.x; e < N_EDGES; e += HC_HIST * 256) {
            const int d = __builtin_nontemporal_load(dst + e);
            rank[e] = (unsigned)atomicAdd(&cnt[d], 1);   // rank among same-dst
        }
    } else {
        const int bid = g - HC_HIST;
        const long long total = (long long)N_NODES * 64;   // padded 4-col units
        for (long long idx = (long long)bid * 256 + threadIdx.x;
             idx < total; idx += (long long)HC_CONCAT * 256) {
            const int n = (int)(idx >> 6);
            const int u = (int)(idx & 63);
            if (u >= 48) continue;
            const int c = u * 4;
            float4 v;
            if (u <= 34) {                               // cols 0..139
                v = *(const float4*)(node_feat + (long long)n * NF_D + c);
            } else if (u <= 42) {                        // cols 140..171
                const int op = opcode[n];
                v = *(const float4*)(op_emb + op * OP_EMB_D + (c - NF_D));
            } else if (u <= 46) {                        // cols 172..187
                const float2 a = *(const float2*)(cfg + (long long)n * CFG_D + (c - 172));
                const float2 b = *(const float2*)(cfg + (long long)n * CFG_D + (c - 172) + 2);
                v.x = a.x; v.y = a.y; v.z = b.x; v.w = b.y;
            } else {                                     // u==47: cols 188..191
                const float2 a = *(const float2*)(cfg + (long long)n * CFG_D + 16);
                v.x = a.x; v.y = a.y; v.z = 0.f; v.w = 0.f;
            }
            uint2 pk;
            pk.x = ((unsigned)f2bf(v.y) << 16) | (unsigned)f2bf(v.x);
            pk.y = ((unsigned)f2bf(v.w) << 16) | (unsigned)f2bf(v.z);
            *(uint2*)(x0 + (long long)n * K_EMB + c) = pk;
        }
    }
}

__global__ __launch_bounds__(256) void blocksum_kernel(const int* __restrict__ cnt,
                                                       int* __restrict__ bsum) {
    const int tid = threadIdx.x, lane = tid & 63, wave = tid >> 6;
    int i = blockIdx.x * 256 + tid;
    int v = (i < N_NODES) ? cnt[i] : 0;
    #pragma unroll
    for (int off = 32; off > 0; off >>= 1) v += __shfl_xor(v, off, 64);
    __shared__ int wsum[4];
    if (lane == 0) wsum[wave] = v;
    __syncthreads();
    if (tid == 0) bsum[blockIdx.x] = wsum[0] + wsum[1] + wsum[2] + wsum[3];
}

__global__ __launch_bounds__(512) void scanbsum_kernel(int* __restrict__ bsum) {
    __shared__ int s[512];
    const int t = threadIdx.x;
    int v0 = (t < NB_SCAN) ? bsum[t] : 0;
    s[t] = v0;
    __syncthreads();
    for (int off = 1; off < 512; off <<= 1) {
        int add = (t >= off) ? s[t - off] : 0;
        __syncthreads();
        s[t] += add;
        __syncthreads();
    }
    if (t < NB_SCAN) bsum[t] = s[t] - v0;   // exclusive
}

__global__ __launch_bounds__(256) void offsets_kernel(const int* __restrict__ cnt,
                                                      const int* __restrict__ bsum,
                                                      int* __restrict__ row_start) {
    const int t = threadIdx.x;
    const int i = blockIdx.x * 256 + t;
    int v0 = (i < N_NODES) ? cnt[i] : 0;
    __shared__ int s[256];
    s[t] = v0;
    __syncthreads();
    for (int off = 1; off < 256; off <<= 1) {
        int add = (t >= off) ? s[t - off] : 0;
        __syncthreads();
        s[t] += add;
        __syncthreads();
    }
    const int excl = s[t] - v0 + bsum[blockIdx.x];
    if (i < N_NODES) row_start[i] = excl;
    if (i == N_NODES - 1) row_start[N_NODES] = excl + v0;  // == N_EDGES
}

// ---------------- merged co-resident: fill (atomic-free) || embed GEMM ----
// 2046 blocks total (<= residency). fill: slot = row_start[dst] + rank,
// range-partitioned (fill_id & 7, preserves XCD heuristic since fill ids are
// the low block ids). embed: A = relu(X0 @ lin_w + lin_b).
__global__ __launch_bounds__(256) void fill_embed_kernel(
    const int* __restrict__ src, const int* __restrict__ dst,
    const unsigned* __restrict__ rank, const int* __restrict__ row_start,
    int* __restrict__ nbr,
    const unsigned short* __restrict__ x0,
    const unsigned short* __restrict__ wemb, const float* __restrict__ lin_b,
    unsigned short* __restrict__ A_bf)
{
    const int g = blockIdx.x;
    if (g < FE_FILL) {
        const int range = g & 7;
        const int lo = range * (N_NODES / 8);
        const int hi = lo + (N_NODES / 8);
        const int groups = FE_FILL >> 3;             // 158
        const int sub = g >> 3;
        for (int e = sub * 256 + threadIdx.x; e < N_EDGES; e += groups * 256) {
            const int d = __builtin_nontemporal_load(dst + e);
            if (d >= lo && d < hi) {
                const int s = __builtin_nontemporal_load(src + e);
                const unsigned rk = rank[e];
                nbr[row_start[d] + rk] = s;          // no atomic
            }
        }
    } else {
        gemm_body<128, K_EMB, true, true, true>(x0, wemb, lin_b, A_bf,
                                                N_NODES, g - FE_FILL);
    }
}

// ---------------- fused per-layer kernel ----------------
// Computes, per 32-node wave tile, in one pass over x:
//   xp = relu(x @ pw + pb)     (wave-private LDS)
//   r  = x @ wr + bl           (fp32, consumed by combine)
//   yp = xp @ wl               (bf16, gathered by combine)
// R6: -30us vs 3 separate GEMMs. Bit-identical numerics.
template <int D>
__global__ __launch_bounds__(256) void fused_layer(
    const unsigned short* __restrict__ x,
    const unsigned short* __restrict__ wpw, const float* __restrict__ pb,
    const unsigned short* __restrict__ wwl,
    const unsigned short* __restrict__ wwr, const float* __restrict__ bl,
    unsigned short* __restrict__ yp, float* __restrict__ rout, int N)
{
    constexpr int MT  = D / 16;        // xp col tiles
    constexpr int KC  = D / 32;        // k tiles
    constexpr int LST = D + 8;         // padded LDS row stride (elements)
    __shared__ unsigned short xpl[4][32][LST];
    const int tid = threadIdx.x, wave = tid >> 6, lane = tid & 63;
    const int wid = blockIdx.x * 4 + wave;
    if (wid >= (N >> 5)) return;
    const int nb   = wid << 5;
    const int l15  = lane & 15;
    const int quad = lane >> 4;

    // ---- stage 1: xp = relu(x@pw+pb) and r = x@wr+bl (shared B-frags) ----
    f32x4 axp[2][MT];
    f32x4 ar[2][4];
    #pragma unroll
    for (int mt = 0; mt < MT; ++mt) {
        #pragma unroll
        for (int q = 0; q < 4; ++q) {
            const float bv = pb[mt * 16 + quad * 4 + q];
            axp[0][mt][q] = bv;
            axp[1][mt][q] = bv;
        }
    }
    #pragma unroll
    for (int mt = 0; mt < 4; ++mt) {
        #pragma unroll
        for (int q = 0; q < 4; ++q) {
            const float bv = bl[mt * 16 + quad * 4 + q];
            ar[0][mt][q] = bv;
            ar[1][mt][q] = bv;
        }
    }
    #pragma unroll
    for (int kc = 0; kc < KC; ++kc) {
        const short8 b0 = ld_frag(x + (long long)(nb + l15)      * D + kc * 32 + quad * 8);
        const short8 b1 = ld_frag(x + (long long)(nb + 16 + l15) * D + kc * 32 + quad * 8);
        #pragma unroll
        for (int mt = 0; mt < MT; ++mt) {
            const short8 a = ld_frag(wpw + ((long long)(kc * MT + mt) * 64 + lane) * 8);
            axp[0][mt] = __builtin_amdgcn_mfma_f32_16x16x32_bf16(a, b0, axp[0][mt], 0, 0, 0);
            axp[1][mt] = __builtin_amdgcn_mfma_f32_16x16x32_bf16(a, b1, axp[1][mt], 0, 0, 0);
        }
        #pragma unroll
        for (int mt = 0; mt < 4; ++mt) {
            const short8 a = ld_frag(wwr + ((long long)(kc * 4 + mt) * 64 + lane) * 8);
            ar[0][mt] = __builtin_amdgcn_mfma_f32_16x16x32_bf16(a, b0, ar[0][mt], 0, 0, 0);
            ar[1][mt] = __builtin_amdgcn_mfma_f32_16x16x32_bf16(a, b1, ar[1][mt], 0, 0, 0);
        }
    }
    // r out (fp32)
    #pragma unroll
    for (int s = 0; s < 2; ++s) {
        float* orow = rout + (long long)(nb + s * 16 + l15) * 64;
        #pragma unroll
        for (int mt = 0; mt < 4; ++mt)
            *(f32x4*)(orow + mt * 16 + quad * 4) = ar[s][mt];
    }
    // relu(xp) -> bf16 -> wave-private LDS in row-major [node][col]
    #pragma unroll
    for (int s = 0; s < 2; ++s) {
        #pragma unroll
        for (int mt = 0; mt < MT; ++mt) {
            float f0 = fmaxf(axp[s][mt][0], 0.f), f1 = fmaxf(axp[s][mt][1], 0.f);
            float f2 = fmaxf(axp[s][mt][2], 0.f), f3 = fmaxf(axp[s][mt][3], 0.f);
            uint2 pk;
            pk.x = ((unsigned)f2bf(f1) << 16) | (unsigned)f2bf(f0);
            pk.y = ((unsigned)f2bf(f3) << 16) | (unsigned)f2bf(f2);
            *(uint2*)&xpl[wave][s * 16 + l15][mt * 16 + quad * 4] = pk;
        }
    }
    asm volatile("s_waitcnt lgkmcnt(0)" ::: "memory");   // same-wave ds ordering

    // ---- stage 2: yp = xp @ wl (B-frags re-read from LDS) ----
    f32x4 ay[2][4];
    #pragma unroll
    for (int mt = 0; mt < 4; ++mt) {
        #pragma unroll
        for (int q = 0; q < 4; ++q) { ay[0][mt][q] = 0.f; ay[1][mt][q] = 0.f; }
    }
    #pragma unroll
    for (int kc = 0; kc < KC; ++kc) {
        const short8 b0 = ld_frag(&xpl[wave][l15]     [kc * 32 + quad * 8]);
        const short8 b1 = ld_frag(&xpl[wave][16 + l15][kc * 32 + quad * 8]);
        #pragma unroll
        for (int mt = 0; mt < 4; ++mt) {
            const short8 a = ld_frag(wwl + ((long long)(kc * 4 + mt) * 64 + lane) * 8);
            ay[0][mt] = __builtin_amdgcn_mfma_f32_16x16x32_bf16(a, b0, ay[0][mt], 0, 0, 0);
            ay[1][mt] = __builtin_amdgcn_mfma_f32_16x16x32_bf16(a, b1, ay[1][mt], 0, 0, 0);
        }
    }
    // yp out (bf16)
    #pragma unroll
    for (int s = 0; s < 2; ++s) {
        unsigned short* orow = yp + (long long)(nb + s * 16 + l15) * 64;
        #pragma unroll
        for (int mt = 0; mt < 4; ++mt) {
            uint2 pk;
            pk.x = ((unsigned)f2bf(ay[s][mt][1]) << 16) | (unsigned)f2bf(ay[s][mt][0]);
            pk.y = ((unsigned)f2bf(ay[s][mt][3]) << 16) | (unsigned)f2bf(ay[s][mt][2]);
            *(uint2*)(orow + mt * 16 + quad * 4) = pk;
        }
    }
}

// ---------------- gather + normalize (root term precomputed as r) ----------------
// R10: software-pipelined — next node's row_start pair and next round's nbr
// vector are prefetched before processing the current one; r load hoisted.
// Same FP order -> bit-identical results.
template <bool OBF16>
__global__ __launch_bounds__(256, 8) void combine_kernel(
    const int* __restrict__ row_start, const int* __restrict__ nbr,
    const unsigned short* __restrict__ yp, const float* __restrict__ r,
    void* __restrict__ out)
{
    const int tid = threadIdx.x, wave = tid >> 6, lane = tid & 63;
    const int stride = gridDim.x * 4;
    int n = blockIdx.x * 4 + wave;
    if (n >= N_NODES) return;
    int rs = row_start[n], re = row_start[n + 1];
    while (true) {
        const int n_next = n + stride;
        int rs2 = 0, re2 = 0;
        if (n_next < N_NODES) {                       // prefetch next node's range
            rs2 = row_start[n_next];
            re2 = row_start[n_next + 1];
        }
        const float rv = r[(long long)n * 64 + lane]; // hoisted root-term load
        float macc[8];
        #pragma unroll
        for (int q = 0; q < 8; ++q) macc[q] = 0.f;
        int my = (rs + lane < re) ? nbr[rs + lane] : 0;
        for (int eb = rs; eb < re; eb += 64) {
            const int ebn = eb + 64;
            int my_next = 0;
            if (ebn < re)                              // prefetch next round's nbr
                my_next = (ebn + lane < re) ? nbr[ebn + lane] : 0;
            const int cnt = min(64, re - eb);
            for (int j2 = 0; j2 < cnt; j2 += 8) {
                #pragma unroll
                for (int q = 0; q < 8; ++q) {
                    const int jj = j2 + q;                       // wave-uniform
                    const int s = __shfl(my, (jj < cnt) ? jj : 0, 64);
                    const float v = bf2f(yp[(long long)s * 64 + lane]);
                    if (jj < cnt) macc[q] += v;                  // uniform predicate
                }
            }
            my = my_next;
        }
        const float m = ((macc[0] + macc[1]) + (macc[2] + macc[3]))
                      + ((macc[4] + macc[5]) + (macc[6] + macc[7]));
        float acc = rv + m / fmaxf((float)(re - rs), 1.0f);
        float sq = acc * acc;
        #pragma unroll
        for (int off = 32; off > 0; off >>= 1) sq += __shfl_xor(sq, off, 64);
        const float res = acc / fmaxf(sqrtf(sq), 1e-12f);
        if (OBF16)
            ((unsigned short*)out)[(long long)n * 64 + lane] = f2bf(res);
        else
            ((float*)out)[(long long)n * 64 + lane] = res;
        if (n_next >= N_NODES) break;
        n = n_next; rs = rs2; re = re2;
    }
}

// ---------------- pooling (block pre-reduction) + head ----------------

__global__ __launch_bounds__(256) void pool_kernel(
    const float* __restrict__ x, const int* __restrict__ batch,
    float* __restrict__ gsum, unsigned* __restrict__ gmax, float* __restrict__ gcnt)
{
    __shared__ float    lsum[2][64];
    __shared__ unsigned lmax[2][64];
    __shared__ int      lcnt[2];
    const int tid = threadIdx.x, wave = tid >> 6, lane = tid & 63;
    if (tid < 128) { lsum[tid >> 6][tid & 63] = 0.f; lmax[tid >> 6][tid & 63] = 0u; }
    if (tid < 2) lcnt[tid] = 0;
    __syncthreads();
    const int base = blockIdx.x * 256;
    const int g0 = batch[base];
    float a0 = 0.f, a1 = 0.f, x0 = -INFINITY, x1 = -INFINITY;
    int c0 = 0, c1 = 0;
    for (int nn = 0; nn < 64; ++nn) {
        const int n = base + wave * 64 + nn;
        if (n >= N_NODES) break;
        const float v = x[(long long)n * 64 + lane];
        const int slot = batch[n] - g0;
        if (slot == 0)      { a0 += v; x0 = fmaxf(x0, v); c0++; }
        else if (slot == 1) { a1 += v; x1 = fmaxf(x1, v); c1++; }
        else {
            const int g = g0 + slot;
            atomicAdd(&gsum[g * 64 + lane], v);
            atomicMax(&gmax[g * 64 + lane], fenc(v));
            if (lane == 0) atomicAdd(&gcnt[g], 1.f);
        }
    }
    if (c0) { atomicAdd(&lsum[0][lane], a0); atomicMax(&lmax[0][lane], fenc(x0));
              if (lane == 0) atomicAdd(&lcnt[0], c0); }
    if (c1) { atomicAdd(&lsum[1][lane], a1); atomicMax(&lmax[1][lane], fenc(x1));
              if (lane == 0) atomicAdd(&lcnt[1], c1); }
    __syncthreads();
    if (tid < 128) {
        const int slot = tid >> 6, k = tid & 63;
        if (lcnt[slot] > 0) {
            const int g = g0 + slot;
            atomicAdd(&gsum[g * 64 + k], lsum[slot][k]);
            atomicMax(&gmax[g * 64 + k], lmax[slot][k]);
            if (k == 0) atomicAdd(&gcnt[g], (float)lcnt[slot]);
        }
    }
}

__global__ void finalize_kernel(const float* __restrict__ gsum, const unsigned* __restrict__ gmax,
                                const float* __restrict__ gcnt, const float* __restrict__ post_w,
                                const float* __restrict__ post_b, float* __restrict__ out)
{
    const int g = blockIdx.x;
    const int k = threadIdx.x;
    const float cnt = gcnt[g];
    const float v = fdec(gmax[g * 64 + k]) + gsum[g * 64 + k] / cnt;
    const float w = post_w[k];
    float sq = v * v, dw = v * w;
    #pragma unroll
    for (int off = 32; off > 0; off >>= 1) {
        sq += __shfl_xor(sq, off, 64);
        dw += __shfl_xor(dw, off, 64);
    }
    if (k == 0) out[g] = dw / sqrtf(sq) + post_b[0];
}

// ---------------- weight pack: fp32 KxM -> bf16 MFMA A-frag layout ----------------
struct WDesc { const float* src; unsigned short* dst; int K, Ksrc, M, off; };
struct WPack { WDesc d[10]; int total; };

__global__ __launch_bounds__(256) void pack_w_kernel(WPack p) {
    const int idx = blockIdx.x * blockDim.x + threadIdx.x;
    if (idx >= p.total) return;
    #pragma unroll
    for (int i = 0; i < 10; ++i) {
        const WDesc d = p.d[i];
        if (idx >= d.off && idx < d.off + d.K * d.M) {
            const int r    = idx - d.off;
            const int kc   = r / (d.M * 32);
            const int rem  = r % (d.M * 32);
            const int mt   = rem / 512;
            const int rem2 = rem % 512;
            const int lane = rem2 >> 3;
            const int j    = rem2 & 7;
            const int k = kc * 32 + (lane >> 4) * 8 + j;
            const int m = mt * 16 + (lane & 15);
            const float v = (k < d.Ksrc) ? d.src[(long long)k * d.M + m] : 0.f;
            d.dst[r] = f2bf(v);
            return;
        }
    }
}

extern "C" void kernel_launch(void* const* d_in, const int* in_sizes, int n_in,
                              void* d_out, int out_size, void* d_ws, size_t ws_size,
                              hipStream_t stream)
{
    const float* node_feat = (const float*)d_in[0];
    const float* cfg       = (const float*)d_in[1];
    const int*   opcode    = (const int*)  d_in[2];
    const int*   edge      = (const int*)  d_in[3];
    const int*   batch     = (const int*)  d_in[4];
    const float* op_emb    = (const float*)d_in[5];
    const float* lin_w     = (const float*)d_in[6];
    const float* lin_b     = (const float*)d_in[7];
    const float* post_w    = (const float*)d_in[8];
    const float* post_b    = (const float*)d_in[9];
    const float* pw[3] = {(const float*)d_in[10], (const float*)d_in[15], (const float*)d_in[20]};
    const float* pb[3] = {(const float*)d_in[11], (const float*)d_in[16], (const float*)d_in[21]};
    const float* wl[3] = {(const float*)d_in[12], (const float*)d_in[17], (const float*)d_in[22]};
    const float* bl[3] = {(const float*)d_in[13], (const float*)d_in[18], (const float*)d_in[23]};
    const float* wr[3] = {(const float*)d_in[14], (const float*)d_in[19], (const float*)d_in[24]};
    const int* srcp = edge;
    const int* dstp = edge + N_EDGES;

    // workspace layout (fp32-element offsets)
    float* ws   = (float*)d_ws;
    int*   nbr       = (int*)(ws + 32000000);  // N_EDGES
    int*   row_start = (int*)(ws + 33600000);  // N+1
    int*   cnt       = (int*)(ws + 33700064);  // N (degree counts)
    int*   bsum      = (int*)(ws + 33800064);  // 512
    float* gsum      = ws + 33825152;          // 64*64
    float* gcnt      = ws + 33829248;          // 64
    unsigned* gmax   = (unsigned*)(ws + 33829312); // 64*64
    unsigned short* wpk_base = (unsigned short*)(ws + 34000000); // 81920 bf16 packed weights

    // packed-weight segment offsets (elements)
    const int OFF_EMB = 0;                  // 192x128
    const int OFF_PW0 = 24576;              // 128x128
    const int OFF_WL0 = 24576 + 16384;      // 128x64
    const int OFF_WR0 = OFF_WL0 + 8192;     // 128x64
    const int OFF_PW1 = OFF_WR0 + 8192;     // 64x64
    const int OFF_WL1 = OFF_PW1 + 4096;
    const int OFF_WR1 = OFF_WL1 + 4096;
    const int OFF_PW2 = OFF_WR1 + 4096;
    const int OFF_WL2 = OFF_PW2 + 4096;
    const int OFF_WR2 = OFF_WL2 + 4096;
    const int W_TOTAL = OFF_WR2 + 4096;     // 81920

    // float-region lifetimes [0, 32M floats):
    unsigned short* A_bf    = (unsigned short*)ws;              // [0,6.4M) N x 128 bf16; dead after fused0
    unsigned short* C2_bf   = (unsigned short*)ws;              // [0,3.2M) over dead A (combine1 out)
    float*          C3      = ws;                               // [0,6.4M) over dead C2 (combine2 out)
    unsigned short* C1_bf   = (unsigned short*)(ws + 6400000);  // [6.4M,9.6M) combine0 out
    unsigned short* X0_bf   = (unsigned short*)(ws + 12800000); // [12.8M,22.4M) N x 192 bf16; dead after embed
    float*          r       = ws + 19200000;                    // [19.2M,25.6M) N x 64 fp32 root term
    unsigned short* yp      = (unsigned short*)(ws + 25600000); // [25.6M,28.8M) N x 64 bf16
    unsigned*       rank    = (unsigned*)(ws + 30000000);       // [30M,31.6M) per-edge rank (u32)

    hipMemsetAsync(cnt, 0, (size_t)N_NODES * 4, stream);
    hipMemsetAsync(gsum, 0, (size_t)(4096 + 64 + 4096) * 4, stream);

    // ---- pack all weights to bf16 MFMA A-frag layout (one tiny kernel) ----
    WPack wp;
    wp.d[0] = { lin_w, wpk_base + OFF_EMB, K_EMB, 190, 128, OFF_EMB };
    wp.d[1] = { pw[0], wpk_base + OFF_PW0, 128, 128, 128, OFF_PW0 };
    wp.d[2] = { wl[0], wpk_base + OFF_WL0, 128, 128,  64, OFF_WL0 };
    wp.d[3] = { wr[0], wpk_base + OFF_WR0, 128, 128,  64, OFF_WR0 };
    wp.d[4] = { pw[1], wpk_base + OFF_PW1,  64,  64,  64, OFF_PW1 };
    wp.d[5] = { wl[1], wpk_base + OFF_WL1,  64,  64,  64, OFF_WL1 };
    wp.d[6] = { wr[1], wpk_base + OFF_WR1,  64,  64,  64, OFF_WR1 };
    wp.d[7] = { pw[2], wpk_base + OFF_PW2,  64,  64,  64, OFF_PW2 };
    wp.d[8] = { wl[2], wpk_base + OFF_WL2,  64,  64,  64, OFF_WL2 };
    wp.d[9] = { wr[2], wpk_base + OFF_WR2,  64,  64,  64, OFF_WR2 };
    wp.total = W_TOTAL;
    pack_w_kernel<<<(W_TOTAL + 255) / 256, 256, 0, stream>>>(wp);

    // ---- hist(+rank) || concat — co-resident (2046 blocks) ----
    hist_concat_kernel<<<HC_HIST + HC_CONCAT, 256, 0, stream>>>(
        dstp, cnt, rank, node_feat, cfg, opcode, op_emb, X0_bf);

    // ---- CSR offsets ----
    blocksum_kernel<<<NB_SCAN, 256, 0, stream>>>(cnt, bsum);
    scanbsum_kernel<<<1, 512, 0, stream>>>(bsum);
    offsets_kernel<<<NB_SCAN, 256, 0, stream>>>(cnt, bsum, row_start);

    // ---- fill (atomic-free) || embed GEMM — co-resident (2046 blocks) ----
    fill_embed_kernel<<<FE_FILL + GEMM_BLKS, 256, 0, stream>>>(
        srcp, dstp, rank, row_start, nbr, X0_bf, wpk_base + OFF_EMB, lin_b, A_bf);

    // ---- layer 0 (D=128): fused {pw,wr,wl} -> yp, r ----
    fused_layer<128><<<GEMM_BLKS, 256, 0, stream>>>(
        A_bf, wpk_base + OFF_PW0, pb[0], wpk_base + OFF_WL0,
        wpk_base + OFF_WR0, bl[0], yp, r, N_NODES);
    combine_kernel<true><<<2048, 256, 0, stream>>>(row_start, nbr, yp, r, C1_bf);

    // ---- layer 1 (D=64) ----
    fused_layer<64><<<GEMM_BLKS, 256, 0, stream>>>(
        C1_bf, wpk_base + OFF_PW1, pb[1], wpk_base + OFF_WL1,
        wpk_base + OFF_WR1, bl[1], yp, r, N_NODES);
    combine_kernel<true><<<2048, 256, 0, stream>>>(row_start, nbr, yp, r, C2_bf);

    // ---- layer 2 (D=64) ----
    fused_layer<64><<<GEMM_BLKS, 256, 0, stream>>>(
        C2_bf, wpk_base + OFF_PW2, pb[2], wpk_base + OFF_WL2,
        wpk_base + OFF_WR2, bl[2], yp, r, N_NODES);
    combine_kernel<false><<<2048, 256, 0, stream>>>(row_start, nbr, yp, r, C3);

    // ---- pooling + head ----
    pool_kernel<<<NB_SCAN, 256, 0, stream>>>(C3, batch, gsum, gmax, gcnt);
    finalize_kernel<<<N_GRAPHS, 64, 0, stream>>>(gsum, gmax, gcnt, post_w, post_b,
                                                 (float*)d_out);
}

// Round 13
// 602.680 us; speedup vs baseline: 1.0491x; 1.0491x over previous
//
#include <hip/hip_runtime.h>
#include <hip/hip_bf16.h>
#include <math.h>

#define N_NODES   100000
#define N_EDGES   1600000
#define N_GRAPHS  64
#define NF_D      140
#define OP_EMB_D  32
#define CFG_D     18
#define K_EMB     192     // 190 zero-padded to 192
#define NB_SCAN   391     // ceil(N_NODES/256)
#define HIST_BLKS 6250    // ceil(N_EDGES/256) — one atomic per thread (R12: grid-stride hist regressed)
#define CONCAT_BLKS 4096
#define FILL_BLKS 2048    // 8 ranges x 256 groups

typedef __attribute__((ext_vector_type(8))) short short8;   // 8 bf16 = 4 VGPRs
typedef __attribute__((ext_vector_type(4))) float f32x4;    // MFMA C/D frag

// monotone float<->uint encoding for atomicMax on floats
__device__ __forceinline__ unsigned fenc(float f) {
    unsigned u = __float_as_uint(f);
    return (u & 0x80000000u) ? ~u : (u | 0x80000000u);
}
__device__ __forceinline__ float fdec(unsigned u) {
    unsigned v = (u & 0x80000000u) ? (u & 0x7FFFFFFFu) : ~u;
    return __uint_as_float(v);
}
// self-contained bf16 pack/unpack (RNE; finite inputs only)
__device__ __forceinline__ unsigned short f2bf(float f) {
    unsigned u = __float_as_uint(f);
    return (unsigned short)((u + 0x7FFFu + ((u >> 16) & 1u)) >> 16);
}
__device__ __forceinline__ float bf2f(unsigned short h) {
    return __uint_as_float((unsigned)h << 16);
}
__device__ __forceinline__ short8 ld_frag(const unsigned short* p) {
    union { uint4 u; short8 s; } c;
    c.u = *(const uint4*)p;
    return c.s;
}

// ---------------- CSR build — final model (R2..R12) ----------------
// Device-scope atomics execute at the memory-side coherence point: ~40B
// WRITE + a latency slot each. Falsified remedies: XCD-local copies (R5),
// L2 read-pre-touch (R7), co-scheduling with streaming work (R8: sum not
// max; R12: co-resident grids made it WORSE — per-wave serialization of
// returning atomics). Best shape: ONE returning atomic per thread (R9),
// rank = atomicAdd return value -> fill needs no atomic at all.

// ---------------- GEMM body (device fn, shared by standalone + merged) ----
// A-operand = packed weights (m = weight-col), B-operand = node rows.
// D layout (m89/m91): col=lane&15 = node, row=quad*4+reg = weight-col.
// One wave = 32 nodes x all M cols; K fully unrolled; no LDS, no barriers.
template <int M, int K, bool BIAS, bool RELU, bool OBF16>
__device__ __forceinline__ void gemm_body(
    const unsigned short* __restrict__ x,
    const unsigned short* __restrict__ wpk, const float* __restrict__ b,
    void* __restrict__ outv, int N, int bid)
{
    constexpr int MT = M / 16;
    constexpr int KC = K / 32;
    const int tid = threadIdx.x, wave = tid >> 6, lane = tid & 63;
    const int wid = bid * 4 + wave;
    if (wid >= (N >> 5)) return;                  // N % 32 == 0
    const int nb   = wid << 5;
    const int l15  = lane & 15;
    const int quad = lane >> 4;

    f32x4 acc[2][MT];
    #pragma unroll
    for (int mt = 0; mt < MT; ++mt) {
        #pragma unroll
        for (int q = 0; q < 4; ++q) {
            const float bv = BIAS ? b[mt * 16 + quad * 4 + q] : 0.f;
            acc[0][mt][q] = bv;
            acc[1][mt][q] = bv;
        }
    }
    #pragma unroll
    for (int kc = 0; kc < KC; ++kc) {
        const short8 b0 = ld_frag(x + (long long)(nb + l15)      * K + kc * 32 + quad * 8);
        const short8 b1 = ld_frag(x + (long long)(nb + 16 + l15) * K + kc * 32 + quad * 8);
        #pragma unroll
        for (int mt = 0; mt < MT; ++mt) {
            const short8 a = ld_frag(wpk + ((long long)(kc * MT + mt) * 64 + lane) * 8);
            acc[0][mt] = __builtin_amdgcn_mfma_f32_16x16x32_bf16(a, b0, acc[0][mt], 0, 0, 0);
            acc[1][mt] = __builtin_amdgcn_mfma_f32_16x16x32_bf16(a, b1, acc[1][mt], 0, 0, 0);
        }
    }
    #pragma unroll
    for (int s = 0; s < 2; ++s) {
        const long long row = nb + s * 16 + l15;
        if (OBF16) {
            unsigned short* orow = (unsigned short*)outv + row * M;
            #pragma unroll
            for (int mt = 0; mt < MT; ++mt) {
                float f0 = acc[s][mt][0], f1 = acc[s][mt][1];
                float f2 = acc[s][mt][2], f3 = acc[s][mt][3];
                if (RELU) {
                    f0 = fmaxf(f0, 0.f); f1 = fmaxf(f1, 0.f);
                    f2 = fmaxf(f2, 0.f); f3 = fmaxf(f3, 0.f);
                }
                uint2 pk;
                pk.x = ((unsigned)f2bf(f1) << 16) | (unsigned)f2bf(f0);
                pk.y = ((unsigned)f2bf(f3) << 16) | (unsigned)f2bf(f2);
                *(uint2*)(orow + mt * 16 + quad * 4) = pk;
            }
        } else {
            float* orow = (float*)outv + row * M;
            #pragma unroll
            for (int mt = 0; mt < MT; ++mt) {
                f32x4 v = acc[s][mt];
                if (RELU) {
                    v[0] = fmaxf(v[0], 0.f); v[1] = fmaxf(v[1], 0.f);
                    v[2] = fmaxf(v[2], 0.f); v[3] = fmaxf(v[3], 0.f);
                }
                *(f32x4*)(orow + mt * 16 + quad * 4) = v;
            }
        }
    }
}

// ---------------- merged: hist(+rank) || concat ----------------
// concat role: div-free indexing — 64 padded 4-col units per node,
// n = idx>>6 (wave-uniform), u = idx&63, lanes 48-63 idle. float4 loads
// (node_feat/op_emb 16B-aligned, cfg via 8B float2 pairs; u==47 special-
// cased: cfg[16..17] + explicit zeros). Bit-identical output.
__global__ __launch_bounds__(256) void hist_concat_kernel(
    const int* __restrict__ dst, int* __restrict__ cnt,
    unsigned* __restrict__ rank,
    const float* __restrict__ node_feat, const float* __restrict__ cfg,
    const int* __restrict__ opcode, const float* __restrict__ op_emb,
    unsigned short* __restrict__ x0)
{
    if (blockIdx.x < HIST_BLKS) {
        const int e = blockIdx.x * 256 + threadIdx.x;
        if (e < N_EDGES) {
            const int d = __builtin_nontemporal_load(dst + e);
            rank[e] = (unsigned)atomicAdd(&cnt[d], 1);   // rank among same-dst
        }
    } else {
        const int bid = blockIdx.x - HIST_BLKS;
        const long long total = (long long)N_NODES * 64;   // padded 4-col units
        for (long long idx = (long long)bid * 256 + threadIdx.x;
             idx < total; idx += (long long)CONCAT_BLKS * 256) {
            const int n = (int)(idx >> 6);
            const int u = (int)(idx & 63);
            if (u >= 48) continue;
            const int c = u * 4;
            float4 v;
            if (u <= 34) {                               // cols 0..139
                v = *(const float4*)(node_feat + (long long)n * NF_D + c);
            } else if (u <= 42) {                        // cols 140..171
                const int op = opcode[n];
                v = *(const float4*)(op_emb + op * OP_EMB_D + (c - NF_D));
            } else if (u <= 46) {                        // cols 172..187
                const float2 a = *(const float2*)(cfg + (long long)n * CFG_D + (c - 172));
                const float2 b = *(const float2*)(cfg + (long long)n * CFG_D + (c - 172) + 2);
                v.x = a.x; v.y = a.y; v.z = b.x; v.w = b.y;
            } else {                                     // u==47: cols 188..191
                const float2 a = *(const float2*)(cfg + (long long)n * CFG_D + 16);
                v.x = a.x; v.y = a.y; v.z = 0.f; v.w = 0.f;
            }
            uint2 pk;
            pk.x = ((unsigned)f2bf(v.y) << 16) | (unsigned)f2bf(v.x);
            pk.y = ((unsigned)f2bf(v.w) << 16) | (unsigned)f2bf(v.z);
            *(uint2*)(x0 + (long long)n * K_EMB + c) = pk;
        }
    }
}

__global__ __launch_bounds__(256) void blocksum_kernel(const int* __restrict__ cnt,
                                                       int* __restrict__ bsum) {
    const int tid = threadIdx.x, lane = tid & 63, wave = tid >> 6;
    int i = blockIdx.x * 256 + tid;
    int v = (i < N_NODES) ? cnt[i] : 0;
    #pragma unroll
    for (int off = 32; off > 0; off >>= 1) v += __shfl_xor(v, off, 64);
    __shared__ int wsum[4];
    if (lane == 0) wsum[wave] = v;
    __syncthreads();
    if (tid == 0) bsum[blockIdx.x] = wsum[0] + wsum[1] + wsum[2] + wsum[3];
}

__global__ __launch_bounds__(512) void scanbsum_kernel(int* __restrict__ bsum) {
    __shared__ int s[512];
    const int t = threadIdx.x;
    int v0 = (t < NB_SCAN) ? bsum[t] : 0;
    s[t] = v0;
    __syncthreads();
    for (int off = 1; off < 512; off <<= 1) {
        int add = (t >= off) ? s[t - off] : 0;
        __syncthreads();
        s[t] += add;
        __syncthreads();
    }
    if (t < NB_SCAN) bsum[t] = s[t] - v0;   // exclusive
}

__global__ __launch_bounds__(256) void offsets_kernel(const int* __restrict__ cnt,
                                                      const int* __restrict__ bsum,
                                                      int* __restrict__ row_start) {
    const int t = threadIdx.x;
    const int i = blockIdx.x * 256 + t;
    int v0 = (i < N_NODES) ? cnt[i] : 0;
    __shared__ int s[256];
    s[t] = v0;
    __syncthreads();
    for (int off = 1; off < 256; off <<= 1) {
        int add = (t >= off) ? s[t - off] : 0;
        __syncthreads();
        s[t] += add;
        __syncthreads();
    }
    const int excl = s[t] - v0 + bsum[blockIdx.x];
    if (i < N_NODES) row_start[i] = excl;
    if (i == N_NODES - 1) row_start[N_NODES] = excl + v0;  // == N_EDGES
}

// ---------------- merged: fill (atomic-free) || embed GEMM ----------------
// fill part: slot = row_start[dst] + rank -> pure streaming scatter, range-
// partitioned (blockIdx&7) to confine the 0.8MB nbr window per XCD L2.
// embed part: A = relu(X0 @ lin_w + lin_b), bf16 out.
__global__ __launch_bounds__(256) void fill_embed_kernel(
    const int* __restrict__ src, const int* __restrict__ dst,
    const unsigned* __restrict__ rank, const int* __restrict__ row_start,
    int* __restrict__ nbr,
    const unsigned short* __restrict__ x0,
    const unsigned short* __restrict__ wemb, const float* __restrict__ lin_b,
    unsigned short* __restrict__ A_bf)
{
    if (blockIdx.x < FILL_BLKS) {
        const int range = blockIdx.x & 7;
        const int lo = range * (N_NODES / 8);
        const int hi = lo + (N_NODES / 8);
        const int groups = FILL_BLKS >> 3;
        const int sub = blockIdx.x >> 3;
        for (int e = sub * 256 + threadIdx.x; e < N_EDGES; e += groups * 256) {
            const int d = __builtin_nontemporal_load(dst + e);
            if (d >= lo && d < hi) {
                const int s = __builtin_nontemporal_load(src + e);
                const unsigned rk = rank[e];
                nbr[row_start[d] + rk] = s;          // no atomic
            }
        }
    } else {
        gemm_body<128, K_EMB, true, true, true>(x0, wemb, lin_b, A_bf,
                                                N_NODES, blockIdx.x - FILL_BLKS);
    }
}

// ---------------- fused per-layer kernel ----------------
// Computes, per 32-node wave tile, in one pass over x:
//   xp = relu(x @ pw + pb)     (wave-private LDS)
//   r  = x @ wr + bl           (fp32, consumed by combine)
//   yp = xp @ wl               (bf16, gathered by combine)
// R6: -30us vs 3 separate GEMMs. Bit-identical numerics.
template <int D>
__global__ __launch_bounds__(256) void fused_layer(
    const unsigned short* __restrict__ x,
    const unsigned short* __restrict__ wpw, const float* __restrict__ pb,
    const unsigned short* __restrict__ wwl,
    const unsigned short* __restrict__ wwr, const float* __restrict__ bl,
    unsigned short* __restrict__ yp, float* __restrict__ rout, int N)
{
    constexpr int MT  = D / 16;        // xp col tiles
    constexpr int KC  = D / 32;        // k tiles
    constexpr int LST = D + 8;         // padded LDS row stride (elements)
    __shared__ unsigned short xpl[4][32][LST];
    const int tid = threadIdx.x, wave = tid >> 6, lane = tid & 63;
    const int wid = blockIdx.x * 4 + wave;
    if (wid >= (N >> 5)) return;
    const int nb   = wid << 5;
    const int l15  = lane & 15;
    const int quad = lane >> 4;

    // ---- stage 1: xp = relu(x@pw+pb) and r = x@wr+bl (shared B-frags) ----
    f32x4 axp[2][MT];
    f32x4 ar[2][4];
    #pragma unroll
    for (int mt = 0; mt < MT; ++mt) {
        #pragma unroll
        for (int q = 0; q < 4; ++q) {
            const float bv = pb[mt * 16 + quad * 4 + q];
            axp[0][mt][q] = bv;
            axp[1][mt][q] = bv;
        }
    }
    #pragma unroll
    for (int mt = 0; mt < 4; ++mt) {
        #pragma unroll
        for (int q = 0; q < 4; ++q) {
            const float bv = bl[mt * 16 + quad * 4 + q];
            ar[0][mt][q] = bv;
            ar[1][mt][q] = bv;
        }
    }
    #pragma unroll
    for (int kc = 0; kc < KC; ++kc) {
        const short8 b0 = ld_frag(x + (long long)(nb + l15)      * D + kc * 32 + quad * 8);
        const short8 b1 = ld_frag(x + (long long)(nb + 16 + l15) * D + kc * 32 + quad * 8);
        #pragma unroll
        for (int mt = 0; mt < MT; ++mt) {
            const short8 a = ld_frag(wpw + ((long long)(kc * MT + mt) * 64 + lane) * 8);
            axp[0][mt] = __builtin_amdgcn_mfma_f32_16x16x32_bf16(a, b0, axp[0][mt], 0, 0, 0);
            axp[1][mt] = __builtin_amdgcn_mfma_f32_16x16x32_bf16(a, b1, axp[1][mt], 0, 0, 0);
        }
        #pragma unroll
        for (int mt = 0; mt < 4; ++mt) {
            const short8 a = ld_frag(wwr + ((long long)(kc * 4 + mt) * 64 + lane) * 8);
            ar[0][mt] = __builtin_amdgcn_mfma_f32_16x16x32_bf16(a, b0, ar[0][mt], 0, 0, 0);
            ar[1][mt] = __builtin_amdgcn_mfma_f32_16x16x32_bf16(a, b1, ar[1][mt], 0, 0, 0);
        }
    }
    // r out (fp32)
    #pragma unroll
    for (int s = 0; s < 2; ++s) {
        float* orow = rout + (long long)(nb + s * 16 + l15) * 64;
        #pragma unroll
        for (int mt = 0; mt < 4; ++mt)
            *(f32x4*)(orow + mt * 16 + quad * 4) = ar[s][mt];
    }
    // relu(xp) -> bf16 -> wave-private LDS in row-major [node][col]
    #pragma unroll
    for (int s = 0; s < 2; ++s) {
        #pragma unroll
        for (int mt = 0; mt < MT; ++mt) {
            float f0 = fmaxf(axp[s][mt][0], 0.f), f1 = fmaxf(axp[s][mt][1], 0.f);
            float f2 = fmaxf(axp[s][mt][2], 0.f), f3 = fmaxf(axp[s][mt][3], 0.f);
            uint2 pk;
            pk.x = ((unsigned)f2bf(f1) << 16) | (unsigned)f2bf(f0);
            pk.y = ((unsigned)f2bf(f3) << 16) | (unsigned)f2bf(f2);
            *(uint2*)&xpl[wave][s * 16 + l15][mt * 16 + quad * 4] = pk;
        }
    }
    asm volatile("s_waitcnt lgkmcnt(0)" ::: "memory");   // same-wave ds ordering

    // ---- stage 2: yp = xp @ wl (B-frags re-read from LDS) ----
    f32x4 ay[2][4];
    #pragma unroll
    for (int mt = 0; mt < 4; ++mt) {
        #pragma unroll
        for (int q = 0; q < 4; ++q) { ay[0][mt][q] = 0.f; ay[1][mt][q] = 0.f; }
    }
    #pragma unroll
    for (int kc = 0; kc < KC; ++kc) {
        const short8 b0 = ld_frag(&xpl[wave][l15]     [kc * 32 + quad * 8]);
        const short8 b1 = ld_frag(&xpl[wave][16 + l15][kc * 32 + quad * 8]);
        #pragma unroll
        for (int mt = 0; mt < 4; ++mt) {
            const short8 a = ld_frag(wwl + ((long long)(kc * 4 + mt) * 64 + lane) * 8);
            ay[0][mt] = __builtin_amdgcn_mfma_f32_16x16x32_bf16(a, b0, ay[0][mt], 0, 0, 0);
            ay[1][mt] = __builtin_amdgcn_mfma_f32_16x16x32_bf16(a, b1, ay[1][mt], 0, 0, 0);
        }
    }
    // yp out (bf16)
    #pragma unroll
    for (int s = 0; s < 2; ++s) {
        unsigned short* orow = yp + (long long)(nb + s * 16 + l15) * 64;
        #pragma unroll
        for (int mt = 0; mt < 4; ++mt) {
            uint2 pk;
            pk.x = ((unsigned)f2bf(ay[s][mt][1]) << 16) | (unsigned)f2bf(ay[s][mt][0]);
            pk.y = ((unsigned)f2bf(ay[s][mt][3]) << 16) | (unsigned)f2bf(ay[s][mt][2]);
            *(uint2*)(orow + mt * 16 + quad * 4) = pk;
        }
    }
}

// ---------------- gather + normalize (root term precomputed as r) ----------------
// Software-pipelined (R10): next node's row_start pair and next round's nbr
// vector prefetched; r load hoisted. Same FP order -> bit-identical.
template <bool OBF16>
__global__ __launch_bounds__(256, 8) void combine_kernel(
    const int* __restrict__ row_start, const int* __restrict__ nbr,
    const unsigned short* __restrict__ yp, const float* __restrict__ r,
    void* __restrict__ out)
{
    const int tid = threadIdx.x, wave = tid >> 6, lane = tid & 63;
    const int stride = gridDim.x * 4;
    int n = blockIdx.x * 4 + wave;
    if (n >= N_NODES) return;
    int rs = row_start[n], re = row_start[n + 1];
    while (true) {
        const int n_next = n + stride;
        int rs2 = 0, re2 = 0;
        if (n_next < N_NODES) {                       // prefetch next node's range
            rs2 = row_start[n_next];
            re2 = row_start[n_next + 1];
        }
        const float rv = r[(long long)n * 64 + lane]; // hoisted root-term load
        float macc[8];
        #pragma unroll
        for (int q = 0; q < 8; ++q) macc[q] = 0.f;
        int my = (rs + lane < re) ? nbr[rs + lane] : 0;
        for (int eb = rs; eb < re; eb += 64) {
            const int ebn = eb + 64;
            int my_next = 0;
            if (ebn < re)                              // prefetch next round's nbr
                my_next = (ebn + lane < re) ? nbr[ebn + lane] : 0;
            const int cnt = min(64, re - eb);
            for (int j2 = 0; j2 < cnt; j2 += 8) {
                #pragma unroll
                for (int q = 0; q < 8; ++q) {
                    const int jj = j2 + q;                       // wave-uniform
                    const int s = __shfl(my, (jj < cnt) ? jj : 0, 64);
                    const float v = bf2f(yp[(long long)s * 64 + lane]);
                    if (jj < cnt) macc[q] += v;                  // uniform predicate
                }
            }
            my = my_next;
        }
        const float m = ((macc[0] + macc[1]) + (macc[2] + macc[3]))
                      + ((macc[4] + macc[5]) + (macc[6] + macc[7]));
        float acc = rv + m / fmaxf((float)(re - rs), 1.0f);
        float sq = acc * acc;
        #pragma unroll
        for (int off = 32; off > 0; off >>= 1) sq += __shfl_xor(sq, off, 64);
        const float res = acc / fmaxf(sqrtf(sq), 1e-12f);
        if (OBF16)
            ((unsigned short*)out)[(long long)n * 64 + lane] = f2bf(res);
        else
            ((float*)out)[(long long)n * 64 + lane] = res;
        if (n_next >= N_NODES) break;
        n = n_next; rs = rs2; re = re2;
    }
}

// ---------------- pooling (block pre-reduction) + head ----------------

__global__ __launch_bounds__(256) void pool_kernel(
    const float* __restrict__ x, const int* __restrict__ batch,
    float* __restrict__ gsum, unsigned* __restrict__ gmax, float* __restrict__ gcnt)
{
    __shared__ float    lsum[2][64];
    __shared__ unsigned lmax[2][64];
    __shared__ int      lcnt[2];
    const int tid = threadIdx.x, wave = tid >> 6, lane = tid & 63;
    if (tid < 128) { lsum[tid >> 6][tid & 63] = 0.f; lmax[tid >> 6][tid & 63] = 0u; }
    if (tid < 2) lcnt[tid] = 0;
    __syncthreads();
    const int base = blockIdx.x * 256;
    const int g0 = batch[base];
    float a0 = 0.f, a1 = 0.f, x0 = -INFINITY, x1 = -INFINITY;
    int c0 = 0, c1 = 0;
    for (int nn = 0; nn < 64; ++nn) {
        const int n = base + wave * 64 + nn;
        if (n >= N_NODES) break;
        const float v = x[(long long)n * 64 + lane];
        const int slot = batch[n] - g0;
        if (slot == 0)      { a0 += v; x0 = fmaxf(x0, v); c0++; }
        else if (slot == 1) { a1 += v; x1 = fmaxf(x1, v); c1++; }
        else {
            const int g = g0 + slot;
            atomicAdd(&gsum[g * 64 + lane], v);
            atomicMax(&gmax[g * 64 + lane], fenc(v));
            if (lane == 0) atomicAdd(&gcnt[g], 1.f);
        }
    }
    if (c0) { atomicAdd(&lsum[0][lane], a0); atomicMax(&lmax[0][lane], fenc(x0));
              if (lane == 0) atomicAdd(&lcnt[0], c0); }
    if (c1) { atomicAdd(&lsum[1][lane], a1); atomicMax(&lmax[1][lane], fenc(x1));
              if (lane == 0) atomicAdd(&lcnt[1], c1); }
    __syncthreads();
    if (tid < 128) {
        const int slot = tid >> 6, k = tid & 63;
        if (lcnt[slot] > 0) {
            const int g = g0 + slot;
            atomicAdd(&gsum[g * 64 + k], lsum[slot][k]);
            atomicMax(&gmax[g * 64 + k], lmax[slot][k]);
            if (k == 0) atomicAdd(&gcnt[g], (float)lcnt[slot]);
        }
    }
}

__global__ void finalize_kernel(const float* __restrict__ gsum, const unsigned* __restrict__ gmax,
                                const float* __restrict__ gcnt, const float* __restrict__ post_w,
                                const float* __restrict__ post_b, float* __restrict__ out)
{
    const int g = blockIdx.x;
    const int k = threadIdx.x;
    const float cnt = gcnt[g];
    const float v = fdec(gmax[g * 64 + k]) + gsum[g * 64 + k] / cnt;
    const float w = post_w[k];
    float sq = v * v, dw = v * w;
    #pragma unroll
    for (int off = 32; off > 0; off >>= 1) {
        sq += __shfl_xor(sq, off, 64);
        dw += __shfl_xor(dw, off, 64);
    }
    if (k == 0) out[g] = dw / sqrtf(sq) + post_b[0];
}

// ---------------- weight pack: fp32 KxM -> bf16 MFMA A-frag layout ----------------
struct WDesc { const float* src; unsigned short* dst; int K, Ksrc, M, off; };
struct WPack { WDesc d[10]; int total; };

__global__ __launch_bounds__(256) void pack_w_kernel(WPack p) {
    const int idx = blockIdx.x * blockDim.x + threadIdx.x;
    if (idx >= p.total) return;
    #pragma unroll
    for (int i = 0; i < 10; ++i) {
        const WDesc d = p.d[i];
        if (idx >= d.off && idx < d.off + d.K * d.M) {
            const int r    = idx - d.off;
            const int kc   = r / (d.M * 32);
            const int rem  = r % (d.M * 32);
            const int mt   = rem / 512;
            const int rem2 = rem % 512;
            const int lane = rem2 >> 3;
            const int j    = rem2 & 7;
            const int k = kc * 32 + (lane >> 4) * 8 + j;
            const int m = mt * 16 + (lane & 15);
            const float v = (k < d.Ksrc) ? d.src[(long long)k * d.M + m] : 0.f;
            d.dst[r] = f2bf(v);
            return;
        }
    }
}

extern "C" void kernel_launch(void* const* d_in, const int* in_sizes, int n_in,
                              void* d_out, int out_size, void* d_ws, size_t ws_size,
                              hipStream_t stream)
{
    const float* node_feat = (const float*)d_in[0];
    const float* cfg       = (const float*)d_in[1];
    const int*   opcode    = (const int*)  d_in[2];
    const int*   edge      = (const int*)  d_in[3];
    const int*   batch     = (const int*)  d_in[4];
    const float* op_emb    = (const float*)d_in[5];
    const float* lin_w     = (const float*)d_in[6];
    const float* lin_b     = (const float*)d_in[7];
    const float* post_w    = (const float*)d_in[8];
    const float* post_b    = (const float*)d_in[9];
    const float* pw[3] = {(const float*)d_in[10], (const float*)d_in[15], (const float*)d_in[20]};
    const float* pb[3] = {(const float*)d_in[11], (const float*)d_in[16], (const float*)d_in[21]};
    const float* wl[3] = {(const float*)d_in[12], (const float*)d_in[17], (const float*)d_in[22]};
    const float* bl[3] = {(const float*)d_in[13], (const float*)d_in[18], (const float*)d_in[23]};
    const float* wr[3] = {(const float*)d_in[14], (const float*)d_in[19], (const float*)d_in[24]};
    const int* srcp = edge;
    const int* dstp = edge + N_EDGES;

    // workspace layout (fp32-element offsets)
    float* ws   = (float*)d_ws;
    int*   nbr       = (int*)(ws + 32000000);  // N_EDGES
    int*   row_start = (int*)(ws + 33600000);  // N+1
    int*   cnt       = (int*)(ws + 33700064);  // N (degree counts)
    int*   bsum      = (int*)(ws + 33800064);  // 512
    float* gsum      = ws + 33825152;          // 64*64
    float* gcnt      = ws + 33829248;          // 64
    unsigned* gmax   = (unsigned*)(ws + 33829312); // 64*64
    unsigned short* wpk_base = (unsigned short*)(ws + 34000000); // 81920 bf16 packed weights

    // packed-weight segment offsets (elements)
    const int OFF_EMB = 0;                  // 192x128
    const int OFF_PW0 = 24576;              // 128x128
    const int OFF_WL0 = 24576 + 16384;      // 128x64
    const int OFF_WR0 = OFF_WL0 + 8192;     // 128x64
    const int OFF_PW1 = OFF_WR0 + 8192;     // 64x64
    const int OFF_WL1 = OFF_PW1 + 4096;
    const int OFF_WR1 = OFF_WL1 + 4096;
    const int OFF_PW2 = OFF_WR1 + 4096;
    const int OFF_WL2 = OFF_PW2 + 4096;
    const int OFF_WR2 = OFF_WL2 + 4096;
    const int W_TOTAL = OFF_WR2 + 4096;     // 81920

    // float-region lifetimes [0, 32M floats):
    unsigned short* A_bf    = (unsigned short*)ws;              // [0,6.4M) N x 128 bf16; dead after fused0
    unsigned short* C2_bf   = (unsigned short*)ws;              // [0,3.2M) over dead A (combine1 out)
    float*          C3      = ws;                               // [0,6.4M) over dead C2 (combine2 out)
    unsigned short* C1_bf   = (unsigned short*)(ws + 6400000);  // [6.4M,9.6M) combine0 out
    unsigned short* X0_bf   = (unsigned short*)(ws + 12800000); // [12.8M,22.4M) N x 192 bf16; dead after embed
    float*          r       = ws + 19200000;                    // [19.2M,25.6M) N x 64 fp32 root term
    unsigned short* yp      = (unsigned short*)(ws + 25600000); // [25.6M,28.8M) N x 64 bf16
    unsigned*       rank    = (unsigned*)(ws + 30000000);       // [30M,31.6M) per-edge rank (u32)

    hipMemsetAsync(cnt, 0, (size_t)N_NODES * 4, stream);
    hipMemsetAsync(gsum, 0, (size_t)(4096 + 64 + 4096) * 4, stream);

    // ---- pack all weights to bf16 MFMA A-frag layout (one tiny kernel) ----
    WPack wp;
    wp.d[0] = { lin_w, wpk_base + OFF_EMB, K_EMB, 190, 128, OFF_EMB };
    wp.d[1] = { pw[0], wpk_base + OFF_PW0, 128, 128, 128, OFF_PW0 };
    wp.d[2] = { wl[0], wpk_base + OFF_WL0, 128, 128,  64, OFF_WL0 };
    wp.d[3] = { wr[0], wpk_base + OFF_WR0, 128, 128,  64, OFF_WR0 };
    wp.d[4] = { pw[1], wpk_base + OFF_PW1,  64,  64,  64, OFF_PW1 };
    wp.d[5] = { wl[1], wpk_base + OFF_WL1,  64,  64,  64, OFF_WL1 };
    wp.d[6] = { wr[1], wpk_base + OFF_WR1,  64,  64,  64, OFF_WR1 };
    wp.d[7] = { pw[2], wpk_base + OFF_PW2,  64,  64,  64, OFF_PW2 };
    wp.d[8] = { wl[2], wpk_base + OFF_WL2,  64,  64,  64, OFF_WL2 };
    wp.d[9] = { wr[2], wpk_base + OFF_WR2,  64,  64,  64, OFF_WR2 };
    wp.total = W_TOTAL;
    pack_w_kernel<<<(W_TOTAL + 255) / 256, 256, 0, stream>>>(wp);

    // ---- hist(+rank) || concat ----
    hist_concat_kernel<<<HIST_BLKS + CONCAT_BLKS, 256, 0, stream>>>(
        dstp, cnt, rank, node_feat, cfg, opcode, op_emb, X0_bf);

    // ---- CSR offsets ----
    blocksum_kernel<<<NB_SCAN, 256, 0, stream>>>(cnt, bsum);
    scanbsum_kernel<<<1, 512, 0, stream>>>(bsum);
    offsets_kernel<<<NB_SCAN, 256, 0, stream>>>(cnt, bsum, row_start);

    const int GW = (N_NODES / 32 + 3) / 4;   // 782 blocks (3125 waves)

    // ---- fill (atomic-free) || embed GEMM ----
    fill_embed_kernel<<<FILL_BLKS + GW, 256, 0, stream>>>(
        srcp, dstp, rank, row_start, nbr, X0_bf, wpk_base + OFF_EMB, lin_b, A_bf);

    // ---- layer 0 (D=128): fused {pw,wr,wl} -> yp, r ----
    fused_layer<128><<<GW, 256, 0, stream>>>(
        A_bf, wpk_base + OFF_PW0, pb[0], wpk_base + OFF_WL0,
        wpk_base + OFF_WR0, bl[0], yp, r, N_NODES);
    combine_kernel<true><<<2048, 256, 0, stream>>>(row_start, nbr, yp, r, C1_bf);

    // ---- layer 1 (D=64) ----
    fused_layer<64><<<GW, 256, 0, stream>>>(
        C1_bf, wpk_base + OFF_PW1, pb[1], wpk_base + OFF_WL1,
        wpk_base + OFF_WR1, bl[1], yp, r, N_NODES);
    combine_kernel<true><<<2048, 256, 0, stream>>>(row_start, nbr, yp, r, C2_bf);

    // ---- layer 2 (D=64) ----
    fused_layer<64><<<GW, 256, 0, stream>>>(
        C2_bf, wpk_base + OFF_PW2, pb[2], wpk_base + OFF_WL2,
        wpk_base + OFF_WR2, bl[2], yp, r, N_NODES);
    combine_kernel<false><<<2048, 256, 0, stream>>>(row_start, nbr, yp, r, C3);

    // ---- pooling + head ----
    pool_kernel<<<NB_SCAN, 256, 0, stream>>>(C3, batch, gsum, gmax, gcnt);
    finalize_kernel<<<N_GRAPHS, 64, 0, stream>>>(gsum, gmax, gcnt, post_w, post_b,
                                                 (float*)d_out);
}